// Round 5
// baseline (362.033 us; speedup 1.0000x reference)
//
#include <hip/hip_runtime.h>

typedef _Float16 half8 __attribute__((ext_vector_type(8)));
typedef float floatx4 __attribute__((ext_vector_type(4)));

#define NB 64
#define NN 2048
#define ND 128
#define NT 1024
#define NSEG 8
#define SEGN 256        // NN / NSEG
#define NC 16           // n-rows per chunk
#define NCHUNK 16       // SEGN / NC

// exp2-domain constants: alpha^2 = 0.5*log2(e); scaling W,targets by alpha
// makes (alpha*d)^2 sums directly usable as log2 exponents.
#define ALPHA 0.84932184f
#define INV_ALPHA 1.17741002f
#define LP2_MAJOR (-1.7369655941662063f)   // log2(0.9/3)
#define LP2_MINOR (-12.321928094887362f)   // log2(0.1/512)

// bare v_exp_f32 (input already in log2 units, always <= 0 here)
__device__ __forceinline__ float fexp2(float x) {
  float r;
  asm("v_exp_f32 %0, %1" : "=v"(r) : "v"(x));
  return r;
}

// DPP row_shr add step for 16-lane inclusive scan (zero-fill at row edge)
template <int CTRL>
__device__ __forceinline__ float dppshr_add(float x) {
  int i = __builtin_bit_cast(int, x);
  int s = __builtin_amdgcn_update_dpp(0, i, CTRL, 0xF, 0xF, true);
  return x + __builtin_bit_cast(float, s);
}
// inclusive scan over l15 within each 16-lane row
__device__ __forceinline__ float scan16(float x) {
  x = dppshr_add<0x111>(x);   // row_shr:1
  x = dppshr_add<0x112>(x);   // row_shr:2
  x = dppshr_add<0x114>(x);   // row_shr:4
  x = dppshr_add<0x118>(x);   // row_shr:8
  return x;
}
// broadcast row-lane-15 value to all 16 lanes of the row:
// src_lane = ((l & 0x10) | 0xF)  ->  offset = (0<<10)|(0xF<<5)|0x10 = 0x1F0
__device__ __forceinline__ float bcast15(float x) {
  int i = __builtin_bit_cast(int, x);
  i = __builtin_amdgcn_ds_swizzle(i, 0x1F0);
  return __builtin_bit_cast(float, i);
}

// ---- prep: W_all (f32, [D][T]) -> alpha-scaled t-major f16 hi/lo [t][d] ------
__global__ void k_prep(const float* __restrict__ W, const float* __restrict__ Wm,
                       _Float16* __restrict__ Wph, _Float16* __restrict__ Wpl) {
  int idx = blockIdx.x * 256 + threadIdx.x;      // 131072 = 1024*128
  int t = idx >> 7, d = idx & 127;
  float x = (t < 512) ? W[d * 512 + t] : Wm[d * 512 + (t - 512)];
  x *= ALPHA;
  _Float16 h = (_Float16)x;
  _Float16 l = (_Float16)(x - (float)h);
  Wph[idx] = h;
  Wpl[idx] = l;
}

// ---- prep: data (f32 [B][N][D]) -> fragment-packed f16 hi/lo -----------------
__global__ void k_prep_data(const float* __restrict__ data,
                            _Float16* __restrict__ Ahp, _Float16* __restrict__ Alp) {
  int idx = blockIdx.x * 256 + threadIdx.x;      // 2,097,152 threads
  int l = idx & 63, kk = (idx >> 6) & 3, ch = (idx >> 8) & 127, b = idx >> 15;
  int row = ch * 16 + (l & 15);
  int dcol = kk * 32 + (l >> 4) * 8;
  const float* src = data + ((size_t)b * NN + row) * ND + dcol;
  floatx4 a0 = *(const floatx4*)src;
  floatx4 a1 = *(const floatx4*)(src + 4);
  half8 h, lo;
#pragma unroll
  for (int j = 0; j < 4; ++j) {
    h[j] = (_Float16)a0[j];
    lo[j] = (_Float16)(a0[j] - (float)h[j]);
    h[4 + j] = (_Float16)a1[j];
    lo[4 + j] = (_Float16)(a1[j] - (float)h[4 + j]);
  }
  size_t o = (size_t)idx * 8;
  *(half8*)(Ahp + o) = h;
  *(half8*)(Alp + o) = lo;
}

// ---- W-fragment load (same lane pattern serves A- or B-operand role) ---------
__device__ __forceinline__ void load_wfrags(const _Float16* __restrict__ Wph,
                                            const _Float16* __restrict__ Wpl,
                                            int tbase, int l15, int lhi,
                                            half8 (&wh)[2][4], half8 (&wl)[2][4]) {
#pragma unroll
  for (int tt = 0; tt < 2; ++tt)
#pragma unroll
    for (int kk = 0; kk < 4; ++kk) {
      int t = tbase + tt * 16 + l15;
      int off = t * 128 + kk * 32 + lhi * 8;
      wh[tt][kk] = *(const half8*)(Wph + off);
      wl[tt][kk] = *(const half8*)(Wpl + off);
    }
}

// ---- pass A: per (b, seg, tblock): sum of (alpha*diff)^2 over segment per t --
// (t-in-lane orientation; unchanged from round 4)
__global__ __launch_bounds__(256, 4)
void k_segsum(const _Float16* __restrict__ Ahp, const _Float16* __restrict__ Alp,
              const float* __restrict__ targets,
              const _Float16* __restrict__ Wph, const _Float16* __restrict__ Wpl,
              float* __restrict__ segsum) {
  int bid = blockIdx.x;
  int seg = bid & 7, tb = (bid >> 3) & 7, b = bid >> 6;   // seg -> XCD
  int tid = threadIdx.x;
  int w = tid >> 6, l = tid & 63;
  int l15 = l & 15, lhi = l >> 4;

  half8 wh[2][4], wl[2][4];
  load_wfrags(Wph, Wpl, tb * 128 + w * 32, l15, lhi, wh, wl);

  int nseg0 = seg * SEGN;
  const _Float16* ahp = Ahp + ((size_t)b * 128 + seg * 16) * 2048;
  const _Float16* alp = Alp + ((size_t)b * 128 + seg * 16) * 2048;
  const float* tgp = targets + (size_t)b * NN + nseg0 + lhi * 4;

  float accs[2] = {0.f, 0.f};
  floatx4 accf[2];
  for (int ch = 0; ch < NCHUNK; ++ch) {
    floatx4 z = {0.f, 0.f, 0.f, 0.f};
    accf[0] = z; accf[1] = z;
#pragma unroll
    for (int kk = 0; kk < 4; ++kk) {
      half8 ah = *(const half8*)(ahp + kk * 512 + l * 8);
      half8 al = *(const half8*)(alp + kk * 512 + l * 8);
#pragma unroll
      for (int tt = 0; tt < 2; ++tt) {
        accf[tt] = __builtin_amdgcn_mfma_f32_16x16x32_f16(ah, wh[tt][kk], accf[tt], 0, 0, 0);
        accf[tt] = __builtin_amdgcn_mfma_f32_16x16x32_f16(ah, wl[tt][kk], accf[tt], 0, 0, 0);
        accf[tt] = __builtin_amdgcn_mfma_f32_16x16x32_f16(al, wh[tt][kk], accf[tt], 0, 0, 0);
      }
    }
    floatx4 tg = *(const floatx4*)tgp * ALPHA;
#pragma unroll
    for (int tt = 0; tt < 2; ++tt) {
      float d0 = tg[0] - accf[tt][0], d1 = tg[1] - accf[tt][1];
      float d2 = tg[2] - accf[tt][2], d3 = tg[3] - accf[tt][3];
      accs[tt] += d0 * d0 + d1 * d1 + d2 * d2 + d3 * d3;
    }
    ahp += 2048; alp += 2048; tgp += NC;
  }
#pragma unroll
  for (int tt = 0; tt < 2; ++tt) {
    float tot = accs[tt];
    tot += __shfl_xor(tot, 16);
    tot += __shfl_xor(tot, 32);
    if (lhi == 0)
      segsum[((size_t)b * NT + tb * 128 + w * 32 + tt * 16 + l15) * NSEG + seg] = tot;
  }
}

// ---- tiny exclusive scan over segments per (b,t) -----------------------------
__global__ void k_scan(const float* __restrict__ segsum, float* __restrict__ carry) {
  int idx = blockIdx.x * 256 + threadIdx.x;   // 65536 = NB*NT
  const float* ss = segsum + (size_t)idx * NSEG;
  float* cr = carry + (size_t)idx * NSEG;
  float a = 0.f;
#pragma unroll
  for (int s = 0; s < NSEG; ++s) { cr[s] = a; a += ss[s]; }
}

// ---- pass C (n-in-lane): col = n = l15, row = t = lhi*4+r (+tile*16) ---------
__global__ __launch_bounds__(256, 4)
void k_main(const _Float16* __restrict__ Ahp, const _Float16* __restrict__ Alp,
            const float* __restrict__ targets,
            const _Float16* __restrict__ Wph, const _Float16* __restrict__ Wpl,
            const float* __restrict__ carry, floatx4* __restrict__ part) {
  int bid = blockIdx.x;
  int seg = bid & 7, tb = (bid >> 3) & 7, b = bid >> 6;
  int tid = threadIdx.x;
  int w = tid >> 6, l = tid & 63;
  int l15 = l & 15, lhi = l >> 4;
  int tbase = tb * 128 + w * 32;

  half8 wh[2][4], wl[2][4];
  load_wfrags(Wph, Wpl, tbase, l15, lhi, wh, wl);

  float prior2 = (tb < 4) ? LP2_MAJOR : LP2_MINOR;   // t<512 <=> tb<4

  // pcc = prior2 - carry_init (constant); run accumulates this block's chunks
  float pcc[2][4], run[2][4];
#pragma unroll
  for (int tt = 0; tt < 2; ++tt)
#pragma unroll
    for (int r = 0; r < 4; ++r) {
      int t = tbase + tt * 16 + lhi * 4 + r;
      pcc[tt][r] = prior2 - carry[((size_t)b * NT + t) * NSEG + seg];
      run[tt][r] = 0.f;
    }

  int nseg0 = seg * SEGN;
  const _Float16* ahp = Ahp + ((size_t)b * 128 + seg * 16) * 2048;
  const _Float16* alp = Alp + ((size_t)b * 128 + seg * 16) * 2048;
  const float* tgp = targets + (size_t)b * NN + nseg0 + l15;
  size_t pbase = ((size_t)b * NN + nseg0) * 8 + tb;

  __shared__ float sm[4][4][16][5];   // [wave][chunk%4][n_local][{m,s1,s2,pad,pad}]
  floatx4 acc[2];
  for (int ch = 0; ch < NCHUNK; ++ch) {
    // GEMM: acc[tile][r] = alpha*XW[n = n0+l15][t = tbase + tile*16 + lhi*4 + r]
    floatx4 z = {0.f, 0.f, 0.f, 0.f};
    acc[0] = z; acc[1] = z;
#pragma unroll
    for (int kk = 0; kk < 4; ++kk) {
      half8 ah = *(const half8*)(ahp + kk * 512 + l * 8);
      half8 al = *(const half8*)(alp + kk * 512 + l * 8);
#pragma unroll
      for (int tt = 0; tt < 2; ++tt) {
        acc[tt] = __builtin_amdgcn_mfma_f32_16x16x32_f16(wh[tt][kk], ah, acc[tt], 0, 0, 0);
        acc[tt] = __builtin_amdgcn_mfma_f32_16x16x32_f16(wh[tt][kk], al, acc[tt], 0, 0, 0);
        acc[tt] = __builtin_amdgcn_mfma_f32_16x16x32_f16(wl[tt][kk], ah, acc[tt], 0, 0, 0);
      }
    }
    float tgs = tgp[0] * ALPHA;   // this lane's n; broadcast across lhi

    float q[2][4], inc[2][4], lp[2][4];
#pragma unroll
    for (int tt = 0; tt < 2; ++tt)
#pragma unroll
      for (int r = 0; r < 4; ++r) {
        float d = tgs - acc[tt][r];
        q[tt][r] = d * d;
      }
    // inclusive scan over n (l15 within 16-lane row), per t-value
#pragma unroll
    for (int tt = 0; tt < 2; ++tt)
#pragma unroll
      for (int r = 0; r < 4; ++r)
        inc[tt][r] = scan16(q[tt][r]);
    // lp = prior2 - (carry_init + run + exclusive) ; exclusive = inc - q
#pragma unroll
    for (int tt = 0; tt < 2; ++tt)
#pragma unroll
      for (int r = 0; r < 4; ++r) {
        float t1 = pcc[tt][r] - run[tt][r];
        lp[tt][r] = t1 + (q[tt][r] - inc[tt][r]);
      }
    // carry forward: row total = inc @ lane15
#pragma unroll
    for (int tt = 0; tt < 2; ++tt)
#pragma unroll
      for (int r = 0; r < 4; ++r)
        run[tt][r] += bcast15(inc[tt][r]);

    // softmax over this wave's 32 t: in-lane 8 + cross-lane xor16/32
    float m = fmaxf(fmaxf(fmaxf(lp[0][0], lp[0][1]), fmaxf(lp[0][2], lp[0][3])),
                    fmaxf(fmaxf(lp[1][0], lp[1][1]), fmaxf(lp[1][2], lp[1][3])));
    m = fmaxf(m, __shfl_xor(m, 16));
    m = fmaxf(m, __shfl_xor(m, 32));
    float s1 = 0.f, s2 = 0.f;
#pragma unroll
    for (int tt = 0; tt < 2; ++tt)
#pragma unroll
      for (int r = 0; r < 4; ++r) {
        float e = fexp2(lp[tt][r] - m);
        s1 += e;
        s2 = fmaf(e, acc[tt][r], s2);
      }
    s1 += __shfl_xor(s1, 16);
    s1 += __shfl_xor(s1, 32);
    s2 += __shfl_xor(s2, 16);
    s2 += __shfl_xor(s2, 32);

    if (l < 16) {
      sm[w][ch & 3][l15][0] = m;
      sm[w][ch & 3][l15][1] = s1;
      sm[w][ch & 3][l15][2] = s2;
    }
    if ((ch & 3) == 3) {               // merge 4 chunks' partials across waves
      __syncthreads();
      if (tid < 64) {
        int c4 = tid >> 4, row = tid & 15;
        float m0 = sm[0][c4][row][0], m1 = sm[1][c4][row][0];
        float m2 = sm[2][c4][row][0], m3 = sm[3][c4][row][0];
        float M = fmaxf(fmaxf(m0, m1), fmaxf(m2, m3));
        float e0 = fexp2(m0 - M), e1 = fexp2(m1 - M);
        float e2 = fexp2(m2 - M), e3 = fexp2(m3 - M);
        float S1 = sm[0][c4][row][1] * e0 + sm[1][c4][row][1] * e1 +
                   sm[2][c4][row][1] * e2 + sm[3][c4][row][1] * e3;
        float S2 = sm[0][c4][row][2] * e0 + sm[1][c4][row][2] * e1 +
                   sm[2][c4][row][2] * e2 + sm[3][c4][row][2] * e3;
        floatx4 v;
        v[0] = M; v[1] = S1; v[2] = S2; v[3] = 0.f;
        part[pbase + (size_t)((ch - 3 + c4) * 16 + row) * 8] = v;
      }
      __syncthreads();
    }
    ahp += 2048; alp += 2048; tgp += NC;
  }
}

// ---- combine 8 tb-partials per (b,n) -----------------------------------------
__global__ void k_combine(const floatx4* __restrict__ part, float* __restrict__ out) {
  int idx = blockIdx.x * 256 + threadIdx.x;   // 131072 = NB*NN
  const floatx4* p = part + (size_t)idx * 8;
  floatx4 v[8];
  float M = -3.4e38f;
#pragma unroll
  for (int j = 0; j < 8; ++j) { v[j] = p[j]; M = fmaxf(M, v[j][0]); }
  float s1 = 0.f, s2 = 0.f;
#pragma unroll
  for (int j = 0; j < 8; ++j) {
    float e = fexp2(v[j][0] - M);
    s1 += v[j][1] * e;
    s2 += v[j][2] * e;
  }
  out[idx] = s2 / s1 * INV_ALPHA;   // undo alpha scale on XW values
}

extern "C" void kernel_launch(void* const* d_in, const int* in_sizes, int n_in,
                              void* d_out, int out_size, void* d_ws, size_t ws_size,
                              hipStream_t stream) {
  const float* data    = (const float*)d_in[0];
  const float* targets = (const float*)d_in[1];
  const float* W       = (const float*)d_in[2];
  const float* Wm      = (const float*)d_in[3];
  float* out = (float*)d_out;

  char* ws = (char*)d_ws;
  const size_t MB = 1u << 20;
  _Float16* Wph  = (_Float16*)ws;                          // 256 KB
  _Float16* Wpl  = (_Float16*)(ws + 256 * 1024);           // 256 KB
  _Float16* Ahp  = (_Float16*)(ws + 512 * 1024);           // 32 MB
  _Float16* Alp  = (_Float16*)(ws + 512 * 1024 + 32 * MB); // 32 MB
  float* segsum  = (float*)(ws + 512 * 1024 + 64 * MB);    // 2 MB
  float* carry   = (float*)(ws + 512 * 1024 + 66 * MB);    // 2 MB
  floatx4* part  = (floatx4*)(ws + 512 * 1024 + 68 * MB);  // 16 MB

  k_prep<<<512, 256, 0, stream>>>(W, Wm, Wph, Wpl);
  k_prep_data<<<8192, 256, 0, stream>>>(data, Ahp, Alp);
  k_segsum<<<NB * NSEG * 8, 256, 0, stream>>>(Ahp, Alp, targets, Wph, Wpl, segsum);
  k_scan<<<(NB * NT) / 256, 256, 0, stream>>>(segsum, carry);
  k_main<<<NB * NSEG * 8, 256, 0, stream>>>(Ahp, Alp, targets, Wph, Wpl, carry, part);
  k_combine<<<(NB * NN) / 256, 256, 0, stream>>>(part, out);
}